// Round 7
// baseline (358.325 us; speedup 1.0000x reference)
//
#include <hip/hip_runtime.h>
#include <math.h>

#define BB 16
#define CC 512
#define HWS 4096
#define EPSV 1e-8f
#define TK 12
#define NEGINF (-3.402823466e+38f)
#define CSPLIT 8
#define CCH (CC / CSPLIT)   // 64 channels per split

typedef float f32x4 __attribute__((ext_vector_type(4)));

// workspace layout (float offsets); all float4-aligned where needed
#define OFF_PFG 0
#define OFF_PBG (BB * HWS)
#define OFF_QN  (2 * BB * HWS)
#define OFF_CF  (3 * BB * HWS)
#define OFF_CB  (4 * BB * HWS)
#define OFF_SN  (5 * BB * HWS)            // supp norms fp[16], bp[16]
#define OFF_PN  (OFF_SN + 2 * BB)         // query proto norms fp[16], bp[16]
#define OFF_CNT (OFF_PN + 2 * BB)         // int counts fg[16], bg[16]
#define OFF_TKI (OFF_CNT + 2 * BB)        // int topk idx [2][16][12]
#define OFF_FMMU (OFF_TKI + 2 * BB * TK)  // 4 encoded-uint minmax slots (+pad)
#define OFF_MFG (OFF_FMMU + 16)           // fg bitmask: BB*128 uint32
#define OFF_MBG (OFF_MFG + BB * 128)      // bg bitmask
#define OFF_PD1 (OFF_MBG + BB * 128)      // partial df: CSPLIT*BB*HWS
#define OFF_PD2 (OFF_PD1 + CSPLIT * BB * HWS)   // partial db
#define OFF_PQQ (OFF_PD2 + CSPLIT * BB * HWS)   // partial qq (k1 only)

__device__ __forceinline__ float sigmoidf_(float x) { return 1.f / (1.f + expf(-x)); }

// monotone float<->uint encoding for atomic min/max
__device__ __forceinline__ unsigned encf_(float f) {
    unsigned u = __float_as_uint(f);
    return (u >> 31) ? ~u : (u | 0x80000000u);
}
__device__ __forceinline__ float decf_(unsigned e) {
    return __uint_as_float((e >> 31) ? (e ^ 0x80000000u) : ~e);
}

// ---------------- K0: support prototype norms + state init ----------------
__global__ void k0_init(const float* __restrict__ sfp, const float* __restrict__ sbp,
                        float* __restrict__ snorm, int* __restrict__ cnts,
                        unsigned* __restrict__ fmmu) {
    if (blockIdx.x == BB) {
        int t = threadIdx.x;
        if (t < 2 * BB) cnts[t] = 0;
        if (t < 4) fmmu[t] = (t & 1) ? 0u : 0xFFFFFFFFu; // [min,max,min,max]
        return;
    }
    int b = blockIdx.x;
    int t = threadIdx.x; // 64 = 1 wave
    float s1 = 0.f, s2 = 0.f;
    for (int c = t; c < CC; c += 64) {
        float v = sfp[b * CC + c]; s1 += v * v;
        float w = sbp[b * CC + c]; s2 += w * w;
    }
    for (int off = 32; off; off >>= 1) {
        s1 += __shfl_down(s1, off);
        s2 += __shfl_down(s2, off);
    }
    if (t == 0) { snorm[b] = sqrtf(s1); snorm[BB + b] = sqrtf(s2); }
}

// ---------------- K1: split-K partial dots (INTERNAL REP=2 FOR PROFILING) ----------------
__global__ __launch_bounds__(256) void k1_dots(const float* __restrict__ q, const float* __restrict__ sfp,
                        const float* __restrict__ sbp,
                        float* __restrict__ p_df, float* __restrict__ p_db,
                        float* __restrict__ p_qq) {
    int b = blockIdx.z, cs = blockIdx.y;
    int hw4 = blockIdx.x * 256 + threadIdx.x; // float4 index 0..1023
    __shared__ float sf[CCH], sb[CCH];
    if (threadIdx.x < CCH) sf[threadIdx.x] = sfp[b * CC + cs * CCH + threadIdx.x];
    else if (threadIdx.x < 2 * CCH) sb[threadIdx.x - CCH] = sbp[b * CC + cs * CCH + (threadIdx.x - CCH)];
    __syncthreads();
    const f32x4* qp4 = (const f32x4*)(q + (size_t)b * CC * HWS + (size_t)cs * CCH * HWS) + hw4;
    for (int rep = 0; rep < 2; rep++) {
        f32x4 df = {0, 0, 0, 0}, db = {0, 0, 0, 0}, qq = {0, 0, 0, 0};
#pragma unroll 1
        for (int jj = 0; jj < CCH; jj += 16) {
            f32x4 v[16];
#pragma unroll
            for (int k = 0; k < 16; k++) v[k] = qp4[(size_t)(jj + k) * (HWS / 4)];
#pragma unroll
            for (int k = 0; k < 16; k++) {
                float a = sf[jj + k], c = sb[jj + k];
                df += v[k] * a;
                db += v[k] * c;
                qq += v[k] * v[k];
            }
        }
        size_t o = (size_t)(cs * BB + b) * (HWS / 4) + hw4;
        ((f32x4*)p_df)[o] = df;
        ((f32x4*)p_db)[o] = db;
        ((f32x4*)p_qq)[o] = qq;
        asm volatile("" ::: "memory");
    }
}

// ---------------- K1b: combine partials -> pred, qnorm, counts, packed masks ----------------
__global__ __launch_bounds__(256) void k1b_comb(const float* __restrict__ p_df, const float* __restrict__ p_db,
                         const float* __restrict__ p_qq, const float* __restrict__ snorm,
                         const float* __restrict__ tau,
                         float* __restrict__ pfg, float* __restrict__ pbg,
                         float* __restrict__ qn, int* __restrict__ cnts,
                         unsigned* __restrict__ mfg, unsigned* __restrict__ mbg) {
    int b = blockIdx.y;
    int tid = threadIdx.x;
    int hw4 = blockIdx.x * 256 + tid; // 0..1023
    float4 df = {0, 0, 0, 0}, db = {0, 0, 0, 0}, qq = {0, 0, 0, 0};
    for (int cs = 0; cs < CSPLIT; cs++) {
        size_t o = (size_t)(cs * BB + b) * (HWS / 4) + hw4;
        float4 a = ((const float4*)p_df)[o];
        float4 c = ((const float4*)p_db)[o];
        float4 e = ((const float4*)p_qq)[o];
        df.x += a.x; df.y += a.y; df.z += a.z; df.w += a.w;
        db.x += c.x; db.y += c.y; db.z += c.z; db.w += c.w;
        qq.x += e.x; qq.y += e.y; qq.z += e.z; qq.w += e.w;
    }
    float snf = fmaxf(snorm[b], EPSV), snb = fmaxf(snorm[BB + b], EPSV);
    float thres_fg = sigmoidf_(tau[0]);
    float thres_bg = 1.f - thres_fg;
    float dfa[4] = {df.x, df.y, df.z, df.w};
    float dba[4] = {db.x, db.y, db.z, db.w};
    float qqa[4] = {qq.x, qq.y, qq.z, qq.w};
    float pfa[4], pba[4], qna[4];
    unsigned nf = 0, nb = 0;
#pragma unroll
    for (int i = 0; i < 4; i++) {
        float na = sqrtf(qqa[i]);
        float den = fmaxf(na, EPSV);
        float simf = dfa[i] / (den * snf);
        float simb = dba[i] / (den * snb);
        float a = 10.f * simb, c2 = 10.f * simf;
        float m = fmaxf(a, c2);
        float ea = expf(a - m), eb = expf(c2 - m);
        float inv = 1.f / (ea + eb);
        pfa[i] = eb * inv;
        pba[i] = ea * inv;
        qna[i] = na;
        nf |= (pfa[i] > thres_fg ? 1u : 0u) << i;
        nb |= (pba[i] > thres_bg ? 1u : 0u) << i;
    }
    float4 opf = {pfa[0], pfa[1], pfa[2], pfa[3]};
    float4 opb = {pba[0], pba[1], pba[2], pba[3]};
    float4 oqn = {qna[0], qna[1], qna[2], qna[3]};
    size_t o = (size_t)b * (HWS / 4) + hw4;
    ((float4*)pfg)[o] = opf;
    ((float4*)pbg)[o] = opb;
    ((float4*)qn)[o] = oqn;
    // pack 4-bit nibbles -> 1 bit/pixel masks (512B per b per class)
    __shared__ unsigned char nibf[256], nibb[256];
    nibf[tid] = (unsigned char)nf;
    nibb[tid] = (unsigned char)nb;
    // wave-level count reduce, one atomic per wave per class
    int cfg = __popc(nf), cbg = __popc(nb);
    for (int off = 32; off; off >>= 1) {
        cfg += __shfl_down(cfg, off);
        cbg += __shfl_down(cbg, off);
    }
    if ((tid & 63) == 0) {
        atomicAdd(&cnts[b], cfg);
        atomicAdd(&cnts[BB + b], cbg);
    }
    __syncthreads();
    if (tid < 32) {
        unsigned wf = 0, wb = 0;
#pragma unroll
        for (int k = 0; k < 8; k++) {
            wf |= ((unsigned)nibf[tid * 8 + k]) << (4 * k);
            wb |= ((unsigned)nibb[tid * 8 + k]) << (4 * k);
        }
        mfg[b * 128 + blockIdx.x * 32 + tid] = wf;
        mbg[b * 128 + blockIdx.x * 32 + tid] = wb;
    }
}

// ---------------- K2: top-12 fallback, only when cnt==0 ----------------
__global__ void k2_topk(const float* __restrict__ pfg, const float* __restrict__ pbg,
                        const int* __restrict__ cnts, int* __restrict__ tki) {
    int id = blockIdx.x;      // 0..31
    int cls = id >> 4, b = id & 15;
    if (cnts[cls * BB + b] > 0) return; // fallback unused -> exact skip
    int t = threadIdx.x; // 256
    __shared__ float vals[HWS];
    __shared__ float rv[256];
    __shared__ int   ri[256];
    const float* pr = cls ? pbg : pfg;
    for (int i = t; i < HWS; i += 256) vals[i] = pr[b * HWS + i];
    __syncthreads();
    for (int k = 0; k < TK; k++) {
        float bv = NEGINF; int bi = HWS;
        for (int i = t; i < HWS; i += 256) {
            float v = vals[i];
            if (v > bv) { bv = v; bi = i; }
        }
        rv[t] = bv; ri[t] = bi;
        __syncthreads();
        for (int s = 128; s; s >>= 1) {
            if (t < s) {
                float ov = rv[t + s]; int oi = ri[t + s];
                if (ov > rv[t] || (ov == rv[t] && oi < ri[t])) { rv[t] = ov; ri[t] = oi; }
            }
            __syncthreads();
        }
        if (t == 0) {
            tki[(cls * BB + b) * TK + k] = ri[0];
            vals[ri[0]] = NEGINF;
        }
        __syncthreads();
    }
}

// ---------------- K3: masked channel sums via bitmask, full-unroll MLP, NO atomics ----------------
__global__ __launch_bounds__(256) void k3_proto(const float* __restrict__ q,
                         const unsigned* __restrict__ mfg, const unsigned* __restrict__ mbg,
                         const int* __restrict__ cnts, const int* __restrict__ tki,
                         float* __restrict__ out_fp, float* __restrict__ out_bp) {
    int b = blockIdx.y;
    int t = threadIdx.x;
    __shared__ unsigned smf[128], smb[128];
    if (t < 128) smf[t] = mfg[b * 128 + t];
    else smb[t - 128] = mbg[b * 128 + (t - 128)];
    __syncthreads();
    int wave = t >> 6, lane = t & 63;
    int c = blockIdx.x * 4 + wave;
    const float* qp = q + (size_t)b * CC * HWS + (size_t)c * HWS;
    const f32x4* qp4 = (const f32x4*)qp;
    f32x4 v[16];
#pragma unroll
    for (int j = 0; j < 16; j++) v[j] = qp4[j * 64 + lane];
    unsigned wf[16], wb[16];
#pragma unroll
    for (int j = 0; j < 16; j++) {
        int w = j * 8 + (lane >> 3);
        int sh = (lane & 7) * 4;
        wf[j] = smf[w] >> sh;
        wb[j] = smb[w] >> sh;
    }
    float sfv = 0.f, sbv = 0.f;
#pragma unroll
    for (int j = 0; j < 16; j++) {
        sfv += (wf[j] & 1 ? v[j].x : 0.f) + (wf[j] & 2 ? v[j].y : 0.f)
             + (wf[j] & 4 ? v[j].z : 0.f) + (wf[j] & 8 ? v[j].w : 0.f);
        sbv += (wb[j] & 1 ? v[j].x : 0.f) + (wb[j] & 2 ? v[j].y : 0.f)
             + (wb[j] & 4 ? v[j].z : 0.f) + (wb[j] & 8 ? v[j].w : 0.f);
    }
    for (int off = 32; off; off >>= 1) {
        sfv += __shfl_down(sfv, off);
        sbv += __shfl_down(sbv, off);
    }
    if (lane == 0) {
        int cntf = cnts[b], cntb = cnts[BB + b];
        float fpv, bpv;
        if (cntf > 0) fpv = sfv / (float)cntf;
        else {
            float tf = 0.f;
            for (int j = 0; j < TK; j++) tf += qp[tki[b * TK + j]];
            fpv = tf / (float)TK;
        }
        if (cntb > 0) bpv = sbv / (float)cntb;
        else {
            float tb = 0.f;
            for (int j = 0; j < TK; j++) tb += qp[tki[(BB + b) * TK + j]];
            bpv = tb / (float)TK;
        }
        out_fp[b * CC + c] = fpv;
        out_bp[b * CC + c] = bpv;
    }
}

// ---------------- K3b: query prototype norms (tiny, 64 KB read) ----------------
__global__ void k3b_pnorm(const float* __restrict__ ofp, const float* __restrict__ obp,
                          float* __restrict__ pnorm) {
    int b = blockIdx.x;
    int t = threadIdx.x; // 64
    float s1 = 0.f, s2 = 0.f;
    for (int c = t; c < CC; c += 64) {
        float v = ofp[b * CC + c]; s1 += v * v;
        float w = obp[b * CC + c]; s2 += w * w;
    }
    for (int off = 32; off; off >>= 1) {
        s1 += __shfl_down(s1, off);
        s2 += __shfl_down(s2, off);
    }
    if (t == 0) { pnorm[b] = sqrtf(s1); pnorm[BB + b] = sqrtf(s2); }
}

// ---------------- K4: split-K partial dots (INTERNAL REP=2 FOR PROFILING) ----------------
__global__ __launch_bounds__(256) void k4_dots(const float* __restrict__ q, const float* __restrict__ ofp,
                        const float* __restrict__ obp,
                        float* __restrict__ p_df, float* __restrict__ p_db) {
    int b = blockIdx.z, cs = blockIdx.y;
    int hw4 = blockIdx.x * 256 + threadIdx.x;
    __shared__ float pf[CCH], pb[CCH];
    if (threadIdx.x < CCH) pf[threadIdx.x] = ofp[b * CC + cs * CCH + threadIdx.x];
    else if (threadIdx.x < 2 * CCH) pb[threadIdx.x - CCH] = obp[b * CC + cs * CCH + (threadIdx.x - CCH)];
    __syncthreads();
    const f32x4* qp4 = (const f32x4*)(q + (size_t)b * CC * HWS + (size_t)cs * CCH * HWS) + hw4;
    for (int rep = 0; rep < 2; rep++) {
        f32x4 df = {0, 0, 0, 0}, db = {0, 0, 0, 0};
#pragma unroll 1
        for (int jj = 0; jj < CCH; jj += 16) {
            f32x4 v[16];
#pragma unroll
            for (int k = 0; k < 16; k++) v[k] = qp4[(size_t)(jj + k) * (HWS / 4)];
#pragma unroll
            for (int k = 0; k < 16; k++) {
                float a = pf[jj + k], c = pb[jj + k];
                df += v[k] * a;
                db += v[k] * c;
            }
        }
        size_t o = (size_t)(cs * BB + b) * (HWS / 4) + hw4;
        ((f32x4*)p_df)[o] = df;
        ((f32x4*)p_db)[o] = db;
        asm volatile("" ::: "memory");
    }
}

// ---------------- K4b: combine -> cosines + global atomic minmax ----------------
__global__ __launch_bounds__(256) void k4b_comb(const float* __restrict__ p_df, const float* __restrict__ p_db,
                         const float* __restrict__ pnorm, const float* __restrict__ qn,
                         float* __restrict__ cf, float* __restrict__ cb,
                         unsigned* __restrict__ fmmu) {
    int b = blockIdx.y;
    int hw4 = blockIdx.x * 256 + threadIdx.x;
    float4 df = {0, 0, 0, 0}, db = {0, 0, 0, 0};
    for (int cs = 0; cs < CSPLIT; cs++) {
        size_t o = (size_t)(cs * BB + b) * (HWS / 4) + hw4;
        float4 a = ((const float4*)p_df)[o];
        float4 c = ((const float4*)p_db)[o];
        df.x += a.x; df.y += a.y; df.z += a.z; df.w += a.w;
        db.x += c.x; db.y += c.y; db.z += c.z; db.w += c.w;
    }
    size_t o = (size_t)b * (HWS / 4) + hw4;
    float4 nv = ((const float4*)qn)[o];
    float pnf = fmaxf(pnorm[b], EPSV), pnb = fmaxf(pnorm[BB + b], EPSV);
    float dfa[4] = {df.x, df.y, df.z, df.w};
    float dba[4] = {db.x, db.y, db.z, db.w};
    float nva[4] = {nv.x, nv.y, nv.z, nv.w};
    float cfa[4], cba[4];
    float mnf = 1e38f, mxf = -1e38f, mnb = 1e38f, mxb = -1e38f;
#pragma unroll
    for (int i = 0; i < 4; i++) {
        float na = fmaxf(nva[i], EPSV);
        cfa[i] = dfa[i] / (na * pnf);
        cba[i] = dba[i] / (na * pnb);
        mnf = fminf(mnf, cfa[i]); mxf = fmaxf(mxf, cfa[i]);
        mnb = fminf(mnb, cba[i]); mxb = fmaxf(mxb, cba[i]);
    }
    float4 ocf = {cfa[0], cfa[1], cfa[2], cfa[3]};
    float4 ocb = {cba[0], cba[1], cba[2], cba[3]};
    ((float4*)cf)[o] = ocf;
    ((float4*)cb)[o] = ocb;
    for (int off = 32; off; off >>= 1) {
        mnf = fminf(mnf, __shfl_down(mnf, off));
        mxf = fmaxf(mxf, __shfl_down(mxf, off));
        mnb = fminf(mnb, __shfl_down(mnb, off));
        mxb = fmaxf(mxb, __shfl_down(mxb, off));
    }
    __shared__ float s4[4][4];
    int wave = threadIdx.x >> 6, lane = threadIdx.x & 63;
    if (lane == 0) { s4[wave][0] = mnf; s4[wave][1] = mxf; s4[wave][2] = mnb; s4[wave][3] = mxb; }
    __syncthreads();
    if (threadIdx.x == 0) {
        float a0 = s4[0][0], a1 = s4[0][1], a2 = s4[0][2], a3 = s4[0][3];
        for (int w = 1; w < 4; w++) {
            a0 = fminf(a0, s4[w][0]);
            a1 = fmaxf(a1, s4[w][1]);
            a2 = fminf(a2, s4[w][2]);
            a3 = fmaxf(a3, s4[w][3]);
        }
        atomicMin(&fmmu[0], encf_(a0));
        atomicMax(&fmmu[1], encf_(a1));
        atomicMin(&fmmu[2], encf_(a2));
        atomicMax(&fmmu[3], encf_(a3));
    }
}

// ---------------- K6: final blend (INTERNAL REP=2 FOR PROFILING) ----------------
__global__ __launch_bounds__(256) void k6_out(const float* __restrict__ q, const float* __restrict__ cf,
                       const float* __restrict__ cb, const unsigned* __restrict__ fmmu,
                       float* __restrict__ out) {
    size_t idx = (size_t)blockIdx.x * 256 + threadIdx.x; // float4 index
    size_t chan = idx >> 10;      // / (HWS/4)
    int h4 = (int)(idx & 1023);
    int b = (int)(chan >> 9);     // / CC
    for (int rep = 0; rep < 2; rep++) {
        float mnf = decf_(fmmu[0]), mxf = decf_(fmmu[1]);
        float mnb = decf_(fmmu[2]), mxb = decf_(fmmu[3]);
        float rf = 1.f / (mxf - mnf), rb = 1.f / (mxb - mnb);
        f32x4 qv = __builtin_nontemporal_load((const f32x4*)q + idx);
        f32x4 c1 = ((const f32x4*)(cf + (size_t)b * HWS))[h4];
        f32x4 c2 = ((const f32x4*)(cb + (size_t)b * HWS))[h4];
        f32x4 o;
        o.x = qv.x * ((c1.x - mnf) * rf) + qv.x * (1.f - (c2.x - mnb) * rb);
        o.y = qv.y * ((c1.y - mnf) * rf) + qv.y * (1.f - (c2.y - mnb) * rb);
        o.z = qv.z * ((c1.z - mnf) * rf) + qv.z * (1.f - (c2.z - mnb) * rb);
        o.w = qv.w * ((c1.w - mnf) * rf) + qv.w * (1.f - (c2.w - mnb) * rb);
        __builtin_nontemporal_store(o, (f32x4*)out + idx);
        asm volatile("" ::: "memory");
    }
}

extern "C" void kernel_launch(void* const* d_in, const int* in_sizes, int n_in,
                              void* d_out, int out_size, void* d_ws, size_t ws_size,
                              hipStream_t stream) {
    const float* sfp = (const float*)d_in[0];
    const float* sbp = (const float*)d_in[1];
    const float* q   = (const float*)d_in[2];
    const float* tau = (const float*)d_in[3];
    float* out = (float*)d_out;
    float* wsf = (float*)d_ws;

    float* pfg = wsf + OFF_PFG;
    float* pbg = wsf + OFF_PBG;
    float* qn  = wsf + OFF_QN;
    float* cf  = wsf + OFF_CF;
    float* cb  = wsf + OFF_CB;
    float* snorm = wsf + OFF_SN;
    float* pnorm = wsf + OFF_PN;
    int*   cnts  = (int*)(wsf + OFF_CNT);
    int*   tki   = (int*)(wsf + OFF_TKI);
    unsigned* fmmu = (unsigned*)(wsf + OFF_FMMU);
    unsigned* mfg  = (unsigned*)(wsf + OFF_MFG);
    unsigned* mbg  = (unsigned*)(wsf + OFF_MBG);
    float* p_df  = wsf + OFF_PD1;
    float* p_db  = wsf + OFF_PD2;
    float* p_qq  = wsf + OFF_PQQ;

    float* out_fp = out + (size_t)BB * CC * HWS;
    float* out_bp = out_fp + BB * CC;

    k0_init<<<BB + 1, 64, 0, stream>>>(sfp, sbp, snorm, cnts, fmmu);
    k1_dots<<<dim3(HWS / 1024, CSPLIT, BB), 256, 0, stream>>>(q, sfp, sbp, p_df, p_db, p_qq);
    k1b_comb<<<dim3(HWS / 1024, BB), 256, 0, stream>>>(p_df, p_db, p_qq, snorm, tau, pfg, pbg, qn, cnts, mfg, mbg);
    k2_topk<<<32, 256, 0, stream>>>(pfg, pbg, cnts, tki);
    k3_proto<<<dim3(CC / 4, BB), 256, 0, stream>>>(q, mfg, mbg, cnts, tki, out_fp, out_bp);
    k3b_pnorm<<<BB, 64, 0, stream>>>(out_fp, out_bp, pnorm);
    k4_dots<<<dim3(HWS / 1024, CSPLIT, BB), 256, 0, stream>>>(q, out_fp, out_bp, p_df, p_db);
    k4b_comb<<<dim3(HWS / 1024, BB), 256, 0, stream>>>(p_df, p_db, pnorm, qn, cf, cb, fmmu);
    k6_out<<<(BB * CC * HWS / 4) / 256, 256, 0, stream>>>(q, cf, cb, fmmu, out);
}

// Round 8
// 318.939 us; speedup vs baseline: 1.1235x; 1.1235x over previous
//
#include <hip/hip_runtime.h>
#include <math.h>

#define BB 16
#define CC 512
#define HWS 4096
#define EPSV 1e-8f
#define TK 12
#define NEGINF (-3.402823466e+38f)
#define CHG 64              // channels per LDS tile group
#define NG (CC / CHG)       // 8 groups

typedef float f32x4 __attribute__((ext_vector_type(4)));

// workspace layout (float offsets)
#define OFF_PFG 0
#define OFF_PBG (BB * HWS)
#define OFF_QN  (2 * BB * HWS)
#define OFF_CF  (3 * BB * HWS)
#define OFF_CB  (4 * BB * HWS)
#define OFF_SN  (5 * BB * HWS)            // supp norms fp[16], bp[16]
#define OFF_PN  (OFF_SN + 2 * BB)         // query proto norms fp[16], bp[16]
#define OFF_CNT (OFF_PN + 2 * BB)         // int counts fg[16], bg[16] (written by k2)
#define OFF_TKI (OFF_CNT + 2 * BB)        // int topk idx [2][16][12]
#define OFF_FMM (OFF_TKI + 2 * BB * TK)   // 4 floats {minf, 1/rangef, minb, 1/rangeb}
#define OFF_PCNT (OFF_FMM + 4)            // int partial counts [2][16][16]
#define OFF_BMM (OFF_PCNT + 2 * BB * 16)  // per-block minmax 256*4 floats
#define OFF_MFG (OFF_BMM + 256 * 4)       // fg bitmask: BB*128 uint32
#define OFF_MBG (OFF_MFG + BB * 128)      // bg bitmask

__device__ __forceinline__ float sigmoidf_(float x) { return 1.f / (1.f + expf(-x)); }

// ---------------- K0: support prototype norms ----------------
__global__ void k0_snorm(const float* __restrict__ sfp, const float* __restrict__ sbp,
                         float* __restrict__ snorm) {
    int b = blockIdx.x;
    int t = threadIdx.x; // 64 = 1 wave
    float s1 = 0.f, s2 = 0.f;
    for (int c = t; c < CC; c += 64) {
        float v = sfp[b * CC + c]; s1 += v * v;
        float w = sbp[b * CC + c]; s2 += w * w;
    }
    for (int off = 32; off; off >>= 1) {
        s1 += __shfl_down(s1, off);
        s2 += __shfl_down(s2, off);
    }
    if (t == 0) { snorm[b] = sqrtf(s1); snorm[BB + b] = sqrtf(s2); }
}

// ---- shared helpers for the LDS-tiled dot kernels ----
__device__ __forceinline__ void loadg_(const float* __restrict__ qb, int g, int wid, int lane,
                                       f32x4* vv) {
#pragma unroll
    for (int i = 0; i < 16; i++)
        vv[i] = *(const f32x4*)(qb + (size_t)(g * CHG + wid + 4 * i) * HWS + lane * 4);
}
__device__ __forceinline__ void storel_(float* __restrict__ tile, int wid, int lane,
                                        const f32x4* vv) {
#pragma unroll
    for (int i = 0; i < 16; i++)
        *(f32x4*)&tile[(wid + 4 * i) * 256 + lane * 4] = vv[i];
}

// ---------------- K1F: full dots vs support protos + softmax + masks (no combine pass) ----
__global__ __launch_bounds__(256) void k1f(const float* __restrict__ q,
        const float* __restrict__ sfp, const float* __restrict__ sbp,
        const float* __restrict__ snorm, const float* __restrict__ tau,
        float* __restrict__ pfg, float* __restrict__ pbg, float* __restrict__ qn,
        int* __restrict__ pcnt, unsigned* __restrict__ mfg, unsigned* __restrict__ mbg) {
    int chunk = blockIdx.x, b = blockIdx.y;
    int tid = threadIdx.x, lane = tid & 63, wid = tid >> 6;
    __shared__ float tile[CHG * 256];
    __shared__ int wcf[4], wcb[4];
    const float* qb = q + (size_t)b * CC * HWS + (size_t)chunk * 256;
    const float* sfb = sfp + b * CC;
    const float* sbb = sbp + b * CC;
    float df = 0.f, db = 0.f, qq = 0.f;
    f32x4 v[16];
    loadg_(qb, 0, wid, lane, v);
#pragma unroll 1
    for (int g = 0; g < NG; g++) {
        if (g) __syncthreads();
        storel_(tile, wid, lane, v);
        __syncthreads();
        if (g + 1 < NG) loadg_(qb, g + 1, wid, lane, v);  // fly under consume
#pragma unroll
        for (int c = 0; c < CHG; c++) {
            float vv = tile[c * 256 + tid];
            df = fmaf(vv, sfb[g * CHG + c], df);
            db = fmaf(vv, sbb[g * CHG + c], db);
            qq = fmaf(vv, vv, qq);
        }
    }
    // epilogue: softmax + stores + ballot masks + block counts
    float thres_fg = sigmoidf_(tau[0]);
    float thres_bg = 1.f - thres_fg;
    float snf = fmaxf(snorm[b], EPSV), snb = fmaxf(snorm[BB + b], EPSV);
    float na = sqrtf(qq);
    float den = fmaxf(na, EPSV);
    float simf = df / (den * snf);
    float simb = db / (den * snb);
    float a = 10.f * simb, c2 = 10.f * simf;
    float m = fmaxf(a, c2);
    float ea = expf(a - m), eb = expf(c2 - m);
    float inv = 1.f / (ea + eb);
    float pf = eb * inv, pb = ea * inv;
    int p = chunk * 256 + tid;
    pfg[b * HWS + p] = pf;
    pbg[b * HWS + p] = pb;
    qn[b * HWS + p] = na;
    unsigned long long balf = __ballot(pf > thres_fg);
    unsigned long long balb = __ballot(pb > thres_bg);
    if (lane == 0) {
        mfg[b * 128 + (p >> 5)] = (unsigned)balf;
        mbg[b * 128 + (p >> 5)] = (unsigned)balb;
        wcf[wid] = (int)__popcll(balf);
        wcb[wid] = (int)__popcll(balb);
    } else if (lane == 32) {
        mfg[b * 128 + (p >> 5)] = (unsigned)(balf >> 32);
        mbg[b * 128 + (p >> 5)] = (unsigned)(balb >> 32);
    }
    __syncthreads();
    if (tid == 0) {
        pcnt[(0 * BB + b) * 16 + chunk] = wcf[0] + wcf[1] + wcf[2] + wcf[3];
        pcnt[(1 * BB + b) * 16 + chunk] = wcb[0] + wcb[1] + wcb[2] + wcb[3];
    }
}

// ---------------- K2: sum counts; top-12 fallback only when cnt==0 ----------------
__global__ void k2_topk(const float* __restrict__ pfg, const float* __restrict__ pbg,
                        const int* __restrict__ pcnt, int* __restrict__ cnts,
                        int* __restrict__ tki) {
    int id = blockIdx.x;      // 0..31
    int cls = id >> 4, b = id & 15;
    int t = threadIdx.x; // 256
    __shared__ int cnt_s;
    if (t == 0) {
        int s = 0;
        for (int j = 0; j < 16; j++) s += pcnt[(cls * BB + b) * 16 + j];
        cnts[cls * BB + b] = s;
        cnt_s = s;
    }
    __syncthreads();
    if (cnt_s > 0) return; // fallback unused -> exact skip
    __shared__ float vals[HWS];
    __shared__ float rv[256];
    __shared__ int   ri[256];
    const float* pr = cls ? pbg : pfg;
    for (int i = t; i < HWS; i += 256) vals[i] = pr[b * HWS + i];
    __syncthreads();
    for (int k = 0; k < TK; k++) {
        float bv = NEGINF; int bi = HWS;
        for (int i = t; i < HWS; i += 256) {
            float v = vals[i];
            if (v > bv) { bv = v; bi = i; }
        }
        rv[t] = bv; ri[t] = bi;
        __syncthreads();
        for (int s = 128; s; s >>= 1) {
            if (t < s) {
                float ov = rv[t + s]; int oi = ri[t + s];
                if (ov > rv[t] || (ov == rv[t] && oi < ri[t])) { rv[t] = ov; ri[t] = oi; }
            }
            __syncthreads();
        }
        if (t == 0) {
            tki[(cls * BB + b) * TK + k] = ri[0];
            vals[ri[0]] = NEGINF;
        }
        __syncthreads();
    }
}

// ---------------- K3: masked channel sums via bitmask (unchanged fast version) --------
__global__ __launch_bounds__(256) void k3_proto(const float* __restrict__ q,
                         const unsigned* __restrict__ mfg, const unsigned* __restrict__ mbg,
                         const int* __restrict__ cnts, const int* __restrict__ tki,
                         float* __restrict__ out_fp, float* __restrict__ out_bp) {
    int b = blockIdx.y;
    int t = threadIdx.x;
    __shared__ unsigned smf[128], smb[128];
    if (t < 128) smf[t] = mfg[b * 128 + t];
    else smb[t - 128] = mbg[b * 128 + (t - 128)];
    __syncthreads();
    int wave = t >> 6, lane = t & 63;
    int c = blockIdx.x * 4 + wave;
    const float* qp = q + (size_t)b * CC * HWS + (size_t)c * HWS;
    const f32x4* qp4 = (const f32x4*)qp;
    f32x4 v[16];
#pragma unroll
    for (int j = 0; j < 16; j++) v[j] = qp4[j * 64 + lane];
    unsigned wf[16], wb[16];
#pragma unroll
    for (int j = 0; j < 16; j++) {
        int w = j * 8 + (lane >> 3);
        int sh = (lane & 7) * 4;
        wf[j] = smf[w] >> sh;
        wb[j] = smb[w] >> sh;
    }
    float sfv = 0.f, sbv = 0.f;
#pragma unroll
    for (int j = 0; j < 16; j++) {
        sfv += (wf[j] & 1 ? v[j].x : 0.f) + (wf[j] & 2 ? v[j].y : 0.f)
             + (wf[j] & 4 ? v[j].z : 0.f) + (wf[j] & 8 ? v[j].w : 0.f);
        sbv += (wb[j] & 1 ? v[j].x : 0.f) + (wb[j] & 2 ? v[j].y : 0.f)
             + (wb[j] & 4 ? v[j].z : 0.f) + (wb[j] & 8 ? v[j].w : 0.f);
    }
    for (int off = 32; off; off >>= 1) {
        sfv += __shfl_down(sfv, off);
        sbv += __shfl_down(sbv, off);
    }
    if (lane == 0) {
        int cntf = cnts[b], cntb = cnts[BB + b];
        float fpv, bpv;
        if (cntf > 0) fpv = sfv / (float)cntf;
        else {
            float tf = 0.f;
            for (int j = 0; j < TK; j++) tf += qp[tki[b * TK + j]];
            fpv = tf / (float)TK;
        }
        if (cntb > 0) bpv = sbv / (float)cntb;
        else {
            float tb = 0.f;
            for (int j = 0; j < TK; j++) tb += qp[tki[(BB + b) * TK + j]];
            bpv = tb / (float)TK;
        }
        out_fp[b * CC + c] = fpv;
        out_bp[b * CC + c] = bpv;
    }
}

// ---------------- K3b: query prototype norms ----------------
__global__ void k3b_pnorm(const float* __restrict__ ofp, const float* __restrict__ obp,
                          float* __restrict__ pnorm) {
    int b = blockIdx.x;
    int t = threadIdx.x; // 64
    float s1 = 0.f, s2 = 0.f;
    for (int c = t; c < CC; c += 64) {
        float v = ofp[b * CC + c]; s1 += v * v;
        float w = obp[b * CC + c]; s2 += w * w;
    }
    for (int off = 32; off; off >>= 1) {
        s1 += __shfl_down(s1, off);
        s2 += __shfl_down(s2, off);
    }
    if (t == 0) { pnorm[b] = sqrtf(s1); pnorm[BB + b] = sqrtf(s2); }
}

// ---------------- K4F: full dots vs query protos + cosines + block minmax ------------
__global__ __launch_bounds__(256) void k4f(const float* __restrict__ q,
        const float* __restrict__ ofp, const float* __restrict__ obp,
        const float* __restrict__ pnorm, const float* __restrict__ qn,
        float* __restrict__ cf, float* __restrict__ cb, float* __restrict__ bmm) {
    int chunk = blockIdx.x, b = blockIdx.y;
    int tid = threadIdx.x, lane = tid & 63, wid = tid >> 6;
    __shared__ float tile[CHG * 256];
    __shared__ float s4[4][4];
    const float* qb = q + (size_t)b * CC * HWS + (size_t)chunk * 256;
    const float* pfb = ofp + b * CC;
    const float* pbb = obp + b * CC;
    float df = 0.f, db = 0.f;
    f32x4 v[16];
    loadg_(qb, 0, wid, lane, v);
#pragma unroll 1
    for (int g = 0; g < NG; g++) {
        if (g) __syncthreads();
        storel_(tile, wid, lane, v);
        __syncthreads();
        if (g + 1 < NG) loadg_(qb, g + 1, wid, lane, v);
#pragma unroll
        for (int c = 0; c < CHG; c++) {
            float vv = tile[c * 256 + tid];
            df = fmaf(vv, pfb[g * CHG + c], df);
            db = fmaf(vv, pbb[g * CHG + c], db);
        }
    }
    float pnf = fmaxf(pnorm[b], EPSV), pnb = fmaxf(pnorm[BB + b], EPSV);
    int p = chunk * 256 + tid;
    float na = fmaxf(qn[b * HWS + p], EPSV);
    float cfv = df / (na * pnf);
    float cbv = db / (na * pnb);
    cf[b * HWS + p] = cfv;
    cb[b * HWS + p] = cbv;
    float mnf = cfv, mxf = cfv, mnb2 = cbv, mxb2 = cbv;
    for (int off = 32; off; off >>= 1) {
        mnf = fminf(mnf, __shfl_down(mnf, off));
        mxf = fmaxf(mxf, __shfl_down(mxf, off));
        mnb2 = fminf(mnb2, __shfl_down(mnb2, off));
        mxb2 = fmaxf(mxb2, __shfl_down(mxb2, off));
    }
    if (lane == 0) { s4[wid][0] = mnf; s4[wid][1] = mxf; s4[wid][2] = mnb2; s4[wid][3] = mxb2; }
    __syncthreads();
    if (tid == 0) {
        float a0 = s4[0][0], a1 = s4[0][1], a2 = s4[0][2], a3 = s4[0][3];
        for (int w = 1; w < 4; w++) {
            a0 = fminf(a0, s4[w][0]);
            a1 = fmaxf(a1, s4[w][1]);
            a2 = fminf(a2, s4[w][2]);
            a3 = fmaxf(a3, s4[w][3]);
        }
        int bid = b * 16 + chunk;
        bmm[bid * 4 + 0] = a0;
        bmm[bid * 4 + 1] = a1;
        bmm[bid * 4 + 2] = a2;
        bmm[bid * 4 + 3] = a3;
    }
}

// ---------------- K5: global minmax over 256 block entries ----------------
__global__ void k5_minmax(const float* __restrict__ bmm, float* __restrict__ fmm) {
    int t = threadIdx.x; // 64
    float mnf = 1e38f, mxf = -1e38f, mnb = 1e38f, mxb = -1e38f;
    for (int j = t; j < 256; j += 64) {
        mnf = fminf(mnf, bmm[j * 4 + 0]);
        mxf = fmaxf(mxf, bmm[j * 4 + 1]);
        mnb = fminf(mnb, bmm[j * 4 + 2]);
        mxb = fmaxf(mxb, bmm[j * 4 + 3]);
    }
    for (int off = 32; off; off >>= 1) {
        mnf = fminf(mnf, __shfl_down(mnf, off));
        mxf = fmaxf(mxf, __shfl_down(mxf, off));
        mnb = fminf(mnb, __shfl_down(mnb, off));
        mxb = fmaxf(mxb, __shfl_down(mxb, off));
    }
    if (t == 0) {
        fmm[0] = mnf;
        fmm[1] = 1.f / (mxf - mnf);
        fmm[2] = mnb;
        fmm[3] = 1.f / (mxb - mnb);
    }
}

// ---------------- K6: final blend ----------------
__global__ __launch_bounds__(256) void k6_out(const float* __restrict__ q, const float* __restrict__ cf,
                       const float* __restrict__ cb, const float* __restrict__ fmm,
                       float* __restrict__ out) {
    size_t idx = (size_t)blockIdx.x * 256 + threadIdx.x; // float4 index
    float mnf = fmm[0], rf = fmm[1], mnb = fmm[2], rb = fmm[3];
    size_t chan = idx >> 10;      // / (HWS/4)
    int h4 = (int)(idx & 1023);
    int b = (int)(chan >> 9);     // / CC
    f32x4 qv = __builtin_nontemporal_load((const f32x4*)q + idx);
    f32x4 c1 = ((const f32x4*)(cf + (size_t)b * HWS))[h4];
    f32x4 c2 = ((const f32x4*)(cb + (size_t)b * HWS))[h4];
    f32x4 o;
    o.x = qv.x * ((c1.x - mnf) * rf) + qv.x * (1.f - (c2.x - mnb) * rb);
    o.y = qv.y * ((c1.y - mnf) * rf) + qv.y * (1.f - (c2.y - mnb) * rb);
    o.z = qv.z * ((c1.z - mnf) * rf) + qv.z * (1.f - (c2.z - mnb) * rb);
    o.w = qv.w * ((c1.w - mnf) * rf) + qv.w * (1.f - (c2.w - mnb) * rb);
    __builtin_nontemporal_store(o, (f32x4*)out + idx);
}

extern "C" void kernel_launch(void* const* d_in, const int* in_sizes, int n_in,
                              void* d_out, int out_size, void* d_ws, size_t ws_size,
                              hipStream_t stream) {
    const float* sfp = (const float*)d_in[0];
    const float* sbp = (const float*)d_in[1];
    const float* q   = (const float*)d_in[2];
    const float* tau = (const float*)d_in[3];
    float* out = (float*)d_out;
    float* wsf = (float*)d_ws;

    float* pfg = wsf + OFF_PFG;
    float* pbg = wsf + OFF_PBG;
    float* qn  = wsf + OFF_QN;
    float* cf  = wsf + OFF_CF;
    float* cb  = wsf + OFF_CB;
    float* snorm = wsf + OFF_SN;
    float* pnorm = wsf + OFF_PN;
    int*   cnts  = (int*)(wsf + OFF_CNT);
    int*   tki   = (int*)(wsf + OFF_TKI);
    float* fmm   = wsf + OFF_FMM;
    int*   pcnt  = (int*)(wsf + OFF_PCNT);
    float* bmm   = wsf + OFF_BMM;
    unsigned* mfg = (unsigned*)(wsf + OFF_MFG);
    unsigned* mbg = (unsigned*)(wsf + OFF_MBG);

    float* out_fp = out + (size_t)BB * CC * HWS;
    float* out_bp = out_fp + BB * CC;

    k0_snorm<<<BB, 64, 0, stream>>>(sfp, sbp, snorm);
    k1f<<<dim3(16, BB), 256, 0, stream>>>(q, sfp, sbp, snorm, tau, pfg, pbg, qn, pcnt, mfg, mbg);
    k2_topk<<<32, 256, 0, stream>>>(pfg, pbg, pcnt, cnts, tki);
    k3_proto<<<dim3(CC / 4, BB), 256, 0, stream>>>(q, mfg, mbg, cnts, tki, out_fp, out_bp);
    k3b_pnorm<<<BB, 64, 0, stream>>>(out_fp, out_bp, pnorm);
    k4f<<<dim3(16, BB), 256, 0, stream>>>(q, out_fp, out_bp, pnorm, qn, cf, cb, bmm);
    k5_minmax<<<1, 64, 0, stream>>>(bmm, fmm);
    k6_out<<<(BB * CC * HWS / 4) / 256, 256, 0, stream>>>(q, cf, cb, fmm, out);
}